// Round 1
// baseline (110.255 us; speedup 1.0000x reference)
//
#include <hip/hip_runtime.h>
#include <hip/hip_bf16.h>
#include <stdint.h>

#define ENT 250000
#define RELSZ 64
#define D 128
#define BATCH 32768
#define KNEG 8

// ---------------- workspace layout (byte offsets) ----------------
// t1       :       0 .. 32768    (64x128 f32)  out_rel - (n_inmap.out_rel) n_inmap
// t2       :   32768 .. 65536    (64x128 f32)  in_rel  - (n_outmap.in_rel) n_outmap
// RR       :   65536 .. 81920    (64x64  f32)  in_rel[i] . out_rel[p]
// C        :   81920 .. 102400   (5120 int)    block bucket counts -> exclusive scan
// keys     :  102400 .. 397312   (294912 u8)   branch keys (pos then neg)
// dest_pos :  397312 .. 528384   (32768 int)
// dest_neg :  528384 .. 1576960  (262144 int)
// buf_pos  : 1576960 .. 1708032  (32768 f32)
// buf_neg  : 1708032 .. 2756608  (262144 f32)

__device__ __forceinline__ float wave_reduce_add(float v) {
#pragma unroll
  for (int off = 32; off > 0; off >>= 1) v += __shfl_xor(v, off, 64);
  return v;
}

__device__ __forceinline__ float block128_reduce(float v, float* lds, int t) {
#pragma unroll
  for (int off = 32; off > 0; off >>= 1) v += __shfl_down(v, off, 64);
  __syncthreads();
  if ((t & 63) == 0) lds[t >> 6] = v;
  __syncthreads();
  return lds[0] + lds[1];
}

__device__ __forceinline__ float logsig(float x) {
  return fminf(x, 0.f) - log1pf(expf(-fabsf(x)));
}

// Precompute t1, t2, RR. grid 64 blocks x 128 threads (block p handles rel row p).
__global__ void k_tables(const float* __restrict__ in_rel, const float* __restrict__ out_rel,
                         const float* __restrict__ in_map, const float* __restrict__ out_map,
                         float* __restrict__ t1, float* __restrict__ t2, float* __restrict__ RR) {
  int p = blockIdx.x, t = threadIdx.x;
  __shared__ float lds[2];
  float im = in_map[p * D + t], om = out_map[p * D + t];
  float ro = out_rel[p * D + t], ri = in_rel[p * D + t];
  float s_im2 = block128_reduce(im * im, lds, t);
  float n_im = im / fmaxf(sqrtf(s_im2), 1e-12f);
  float s_om2 = block128_reduce(om * om, lds, t);
  float n_om = om / fmaxf(sqrtf(s_om2), 1e-12f);
  float d1 = block128_reduce(n_im * ro, lds, t);
  float d2 = block128_reduce(n_om * ri, lds, t);
  t1[p * D + t] = ro - d1 * n_im;
  t2[p * D + t] = ri - d2 * n_om;
  for (int q = 0; q < RELSZ; q++) {
    float s = block128_reduce(ri * out_rel[q * D + t], lds, t);
    if (t == 0) RR[p * RELSZ + q] = s;
  }
}

// Keys + per-block bucket counts. blocks [0,128): pos chunks; [128,1152): neg chunks. 256 thr.
// Count layout: pos -> C[v*128 + blk]; neg -> C[512 + v*1024 + (blk-128)].
__global__ void k_count(const int* __restrict__ in_lab, const int* __restrict__ pos_lab,
                        const int* __restrict__ neg_lab, uint8_t* __restrict__ keys,
                        int* __restrict__ C) {
  int blk = blockIdx.x, t = threadIdx.x;
  int wave = t >> 6, lane = t & 63;
  int key;
  if (blk < 128) {
    int i = blk * 256 + t;
    int il = in_lab[i], pl = pos_lab[i];
    key = ((il >= ENT) ? 2 : 0) | ((pl >= ENT) ? 1 : 0);
    keys[i] = (uint8_t)key;
  } else {
    int i = (blk - 128) * 256 + t;
    int il = in_lab[i >> 3], nl = neg_lab[i];
    key = ((il >= ENT) ? 2 : 0) | ((nl >= ENT) ? 1 : 0);
    keys[BATCH + i] = (uint8_t)key;
  }
  __shared__ int wc[4][4];
  unsigned long long m[4];
#pragma unroll
  for (int v = 0; v < 4; v++) m[v] = __ballot(key == v);
  if (lane < 4) wc[wave][lane] = __popcll(m[lane]);
  __syncthreads();
  if (t < 4) {
    int s = wc[0][t] + wc[1][t] + wc[2][t] + wc[3][t];
    int idx = (blk < 128) ? (t * 128 + blk) : (512 + t * 1024 + (blk - 128));
    C[idx] = s;
  }
}

// In-place exclusive scan of C[0..4607] (1 block, 1024 threads, 5 elems each).
__global__ void k_scan(int* __restrict__ C) {
  __shared__ int tot[1024];
  int t = threadIdx.x;
  int base = t * 5;
  int v[5], e[5];
  int s = 0;
#pragma unroll
  for (int j = 0; j < 5; j++) {
    v[j] = (base + j < 4608) ? C[base + j] : 0;
    e[j] = s;
    s += v[j];
  }
  tot[t] = s;
  __syncthreads();
  for (int off = 1; off < 1024; off <<= 1) {
    int x = (t >= off) ? tot[t - off] : 0;
    __syncthreads();
    tot[t] += x;
    __syncthreads();
  }
  int myoff = (t == 0) ? 0 : tot[t - 1];
#pragma unroll
  for (int j = 0; j < 5; j++)
    if (base + j < 4608) C[base + j] = e[j] + myoff;
}

// Stable destinations: dest = bucket_base + earlier_blocks_same_bucket + in-block stable rank.
__global__ void k_dest(const uint8_t* __restrict__ keys, const int* __restrict__ C,
                       int* __restrict__ dest_pos, int* __restrict__ dest_neg) {
  int blk = blockIdx.x, t = threadIdx.x;
  int wave = t >> 6, lane = t & 63;
  bool is_pos = blk < 128;
  int i, key;
  if (is_pos) { i = blk * 256 + t; key = keys[i]; }
  else        { i = (blk - 128) * 256 + t; key = keys[BATCH + i]; }
  __shared__ int wc[4][4];
  unsigned long long m[4];
#pragma unroll
  for (int v = 0; v < 4; v++) m[v] = __ballot(key == v);
  if (lane < 4) wc[wave][lane] = __popcll(m[lane]);
  int wrank = __popcll(m[key] & ((1ull << lane) - 1ull));
  __syncthreads();
  int wpre = 0;
  for (int w = 0; w < wave; w++) wpre += wc[w][key];
  int idx = is_pos ? (key * 128 + blk) : (512 + key * 1024 + (blk - 128));
  int dest = C[idx] + wpre + wrank;
  if (is_pos) dest_pos[i] = dest;
  else        dest_neg[i] = dest - BATCH;
}

// Main: one wave per input row b; compute 9 dots (pos + 8 neg), scatter logsig values.
__global__ void k_main(const float* __restrict__ in_ent, const float* __restrict__ out_ent,
                       const float* __restrict__ t1, const float* __restrict__ t2,
                       const float* __restrict__ RR,
                       const int* __restrict__ in_lab, const int* __restrict__ pos_lab,
                       const int* __restrict__ neg_lab,
                       const int* __restrict__ dest_pos, const int* __restrict__ dest_neg,
                       float* __restrict__ buf_pos, float* __restrict__ buf_neg) {
  int b = (blockIdx.x * blockDim.x + threadIdx.x) >> 6;
  int lane = threadIdx.x & 63;
  int il = in_lab[b];
  bool ei = il < ENT;
  int iid = ei ? il : il - ENT;
  const float* Lp = ei ? (in_ent + (size_t)iid * D) : (t2 + iid * D);
  float2 L = *(const float2*)(Lp + lane * 2);

  int ol[9];
  ol[0] = pos_lab[b];
#pragma unroll
  for (int j = 0; j < 8; j++) ol[j + 1] = neg_lab[b * 8 + j];

  float2 Rv[9];
#pragma unroll
  for (int j = 0; j < 9; j++) {
    int o = ol[j];
    bool e = o < ENT;
    int oid = e ? o : o - ENT;
    const float* Rp = e ? (out_ent + (size_t)oid * D) : (t1 + oid * D);
    Rv[j] = *(const float2*)(Rp + lane * 2);
  }

#pragma unroll
  for (int j = 0; j < 9; j++) {
    float p = L.x * Rv[j].x + L.y * Rv[j].y;
    float dot = wave_reduce_add(p);
    if (!ei && ol[j] >= ENT) dot = RR[iid * RELSZ + (ol[j] - ENT)];  // rel-rel branch
    if (lane == 0) {
      if (j == 0) buf_pos[dest_pos[b]] = logsig(dot);
      else        buf_neg[dest_neg[b * 8 + j - 1]] = logsig(-dot);
    }
  }
}

// out[j] = -(buf_pos[j] + sum_{t<8} buf_neg[8j+t])
__global__ void k_combine(const float* __restrict__ buf_pos, const float* __restrict__ buf_neg,
                          float* __restrict__ out) {
  int j = blockIdx.x * blockDim.x + threadIdx.x;
  if (j >= BATCH) return;
  float4 a = ((const float4*)buf_neg)[j * 2];
  float4 b = ((const float4*)buf_neg)[j * 2 + 1];
  float s = a.x + a.y + a.z + a.w + b.x + b.y + b.z + b.w;
  out[j] = -(buf_pos[j] + s);
}

extern "C" void kernel_launch(void* const* d_in, const int* in_sizes, int n_in,
                              void* d_out, int out_size, void* d_ws, size_t ws_size,
                              hipStream_t stream) {
  const float* in_ent  = (const float*)d_in[0];
  const float* out_ent = (const float*)d_in[1];
  const float* in_rel  = (const float*)d_in[2];
  const float* out_rel = (const float*)d_in[3];
  const float* in_map  = (const float*)d_in[4];
  const float* out_map = (const float*)d_in[5];
  const int* in_lab  = (const int*)d_in[6];
  const int* pos_lab = (const int*)d_in[7];
  const int* neg_lab = (const int*)d_in[8];

  char* ws = (char*)d_ws;
  float*   t1       = (float*)(ws + 0);
  float*   t2       = (float*)(ws + 32768);
  float*   RR       = (float*)(ws + 65536);
  int*     C        = (int*)(ws + 81920);
  uint8_t* keys     = (uint8_t*)(ws + 102400);
  int*     dest_pos = (int*)(ws + 397312);
  int*     dest_neg = (int*)(ws + 528384);
  float*   buf_pos  = (float*)(ws + 1576960);
  float*   buf_neg  = (float*)(ws + 1708032);
  float*   out      = (float*)d_out;

  k_tables<<<64, 128, 0, stream>>>(in_rel, out_rel, in_map, out_map, t1, t2, RR);
  k_count<<<1152, 256, 0, stream>>>(in_lab, pos_lab, neg_lab, keys, C);
  k_scan<<<1, 1024, 0, stream>>>(C);
  k_dest<<<1152, 256, 0, stream>>>(keys, C, dest_pos, dest_neg);
  k_main<<<8192, 256, 0, stream>>>(in_ent, out_ent, t1, t2, RR,
                                   in_lab, pos_lab, neg_lab, dest_pos, dest_neg,
                                   buf_pos, buf_neg);
  k_combine<<<128, 256, 0, stream>>>(buf_pos, buf_neg, out);
}

// Round 2
// 53.929 us; speedup vs baseline: 2.0445x; 2.0445x over previous
//
#include <hip/hip_runtime.h>
#include <hip/hip_bf16.h>
#include <stdint.h>

#define ENT 250000
#define RELSZ 64
#define D 128
#define BATCH 32768
#define KNEG 8

// ---------------- workspace layout (byte offsets) ----------------
// t1       :       0 .. 32768    (64x128 f32)  out_rel - (n_inmap.out_rel) n_inmap
// t2       :   32768 .. 65536    (64x128 f32)  in_rel  - (n_outmap.in_rel) n_outmap
// RR       :   65536 .. 81920    (64x64  f32)  in_rel[i] . out_rel[p]
// C        :   81920 .. 102400   (5120 int)    block bucket counts -> exclusive scan
// keys     :  102400 .. 397312   (294912 u8)   branch keys (pos then neg)
// dest_pos :  397312 .. 528384   (32768 int)
// dest_neg :  528384 .. 1576960  (262144 int)
// buf_pos  : 1576960 .. 1708032  (32768 f32)
// buf_neg  : 1708032 .. 2756608  (262144 f32)

__device__ __forceinline__ float block128_reduce(float v, float* lds, int t) {
#pragma unroll
  for (int off = 32; off > 0; off >>= 1) v += __shfl_down(v, off, 64);
  __syncthreads();
  if ((t & 63) == 0) lds[t >> 6] = v;
  __syncthreads();
  return lds[0] + lds[1];
}

__device__ __forceinline__ float logsig(float x) {
  return fminf(x, 0.f) - log1pf(expf(-fabsf(x)));
}

// Precompute t1, t2, RR. grid 64 blocks x 128 threads (block p handles rel row p).
__global__ void k_tables(const float* __restrict__ in_rel, const float* __restrict__ out_rel,
                         const float* __restrict__ in_map, const float* __restrict__ out_map,
                         float* __restrict__ t1, float* __restrict__ t2, float* __restrict__ RR) {
  int p = blockIdx.x, t = threadIdx.x;
  __shared__ float lds[2];
  __shared__ float sri[128];
  float im = in_map[p * D + t], om = out_map[p * D + t];
  float ro = out_rel[p * D + t], ri = in_rel[p * D + t];
  float s_im2 = block128_reduce(im * im, lds, t);
  float n_im = im / fmaxf(sqrtf(s_im2), 1e-12f);
  float s_om2 = block128_reduce(om * om, lds, t);
  float n_om = om / fmaxf(sqrtf(s_om2), 1e-12f);
  float d1 = block128_reduce(n_im * ro, lds, t);
  float d2 = block128_reduce(n_om * ri, lds, t);
  t1[p * D + t] = ro - d1 * n_im;
  t2[p * D + t] = ri - d2 * n_om;
  sri[t] = ri;
  __syncthreads();
  if (t < RELSZ) {
    const float* rq = out_rel + t * D;
    float s = 0.f;
#pragma unroll 8
    for (int d = 0; d < D; d += 4) {
      float4 r4 = *(const float4*)(rq + d);
      s += sri[d] * r4.x + sri[d + 1] * r4.y + sri[d + 2] * r4.z + sri[d + 3] * r4.w;
    }
    RR[p * RELSZ + t] = s;
  }
}

// Keys + per-block bucket counts. blocks [0,128): pos chunks; [128,1152): neg chunks. 256 thr.
// Count layout: pos -> C[v*128 + blk]; neg -> C[512 + v*1024 + (blk-128)].
__global__ void k_count(const int* __restrict__ in_lab, const int* __restrict__ pos_lab,
                        const int* __restrict__ neg_lab, uint8_t* __restrict__ keys,
                        int* __restrict__ C) {
  int blk = blockIdx.x, t = threadIdx.x;
  int wave = t >> 6, lane = t & 63;
  int key;
  if (blk < 128) {
    int i = blk * 256 + t;
    int il = in_lab[i], pl = pos_lab[i];
    key = ((il >= ENT) ? 2 : 0) | ((pl >= ENT) ? 1 : 0);
    keys[i] = (uint8_t)key;
  } else {
    int i = (blk - 128) * 256 + t;
    int il = in_lab[i >> 3], nl = neg_lab[i];
    key = ((il >= ENT) ? 2 : 0) | ((nl >= ENT) ? 1 : 0);
    keys[BATCH + i] = (uint8_t)key;
  }
  __shared__ int wc[4][4];
  unsigned long long m[4];
#pragma unroll
  for (int v = 0; v < 4; v++) m[v] = __ballot(key == v);
  if (lane < 4) wc[wave][lane] = __popcll(m[lane]);
  __syncthreads();
  if (t < 4) {
    int s = wc[0][t] + wc[1][t] + wc[2][t] + wc[3][t];
    int idx = (blk < 128) ? (t * 128 + blk) : (512 + t * 1024 + (blk - 128));
    C[idx] = s;
  }
}

// In-place exclusive scan of C[0..4607]. 1 block x 256 threads, 18 elems each.
__global__ void k_scan(int* __restrict__ C) {
  int t = threadIdx.x, lane = t & 63, w = t >> 6;
  int base = t * 18;
  int v[18];
  int s = 0;
#pragma unroll
  for (int j = 0; j < 18; j++) { v[j] = C[base + j]; s += v[j]; }
  int inc = s;
#pragma unroll
  for (int off = 1; off < 64; off <<= 1) {
    int x = __shfl_up(inc, off, 64);
    if (lane >= off) inc += x;
  }
  __shared__ int wsum[4];
  if (lane == 63) wsum[w] = inc;
  __syncthreads();
  int wpre = 0;
  for (int i = 0; i < w; i++) wpre += wsum[i];
  int run = wpre + inc - s;  // exclusive prefix of this thread's chunk
#pragma unroll
  for (int j = 0; j < 18; j++) { C[base + j] = run; run += v[j]; }
}

// Stable destinations: dest = bucket_base + earlier_blocks_same_bucket + in-block stable rank.
__global__ void k_dest(const uint8_t* __restrict__ keys, const int* __restrict__ C,
                       int* __restrict__ dest_pos, int* __restrict__ dest_neg) {
  int blk = blockIdx.x, t = threadIdx.x;
  int wave = t >> 6, lane = t & 63;
  bool is_pos = blk < 128;
  int i, key;
  if (is_pos) { i = blk * 256 + t; key = keys[i]; }
  else        { i = (blk - 128) * 256 + t; key = keys[BATCH + i]; }
  __shared__ int wc[4][4];
  unsigned long long m[4];
#pragma unroll
  for (int v = 0; v < 4; v++) m[v] = __ballot(key == v);
  if (lane < 4) wc[wave][lane] = __popcll(m[lane]);
  int wrank = __popcll(m[key] & ((1ull << lane) - 1ull));
  __syncthreads();
  int wpre = 0;
  for (int w = 0; w < wave; w++) wpre += wc[w][key];
  int idx = is_pos ? (key * 128 + blk) : (512 + key * 1024 + (blk - 128));
  int dest = C[idx] + wpre + wrank;
  if (is_pos) dest_pos[i] = dest;
  else        dest_neg[i] = dest - BATCH;
}

// Main: one wave per input row b. 16 lanes per pair, 4 pairs per round, 3 rounds.
// All global loads issued up front for MLP; reductions are 4-deep within 16 lanes.
__global__ void k_main(const float* __restrict__ in_ent, const float* __restrict__ out_ent,
                       const float* __restrict__ t1, const float* __restrict__ t2,
                       const float* __restrict__ RR,
                       const int* __restrict__ in_lab, const int* __restrict__ pos_lab,
                       const int* __restrict__ neg_lab,
                       const int* __restrict__ dest_pos, const int* __restrict__ dest_neg,
                       float* __restrict__ buf_pos, float* __restrict__ buf_neg) {
  int b = (blockIdx.x * blockDim.x + threadIdx.x) >> 6;
  int lane = threadIdx.x & 63;
  int q = lane & 15, g = lane >> 4;

  int il = in_lab[b];
  bool ei = il < ENT;
  int iid = ei ? il : il - ENT;
  const float* Lp = ei ? (in_ent + (size_t)iid * D) : (t2 + (size_t)iid * D);
  float4 La = *(const float4*)(Lp + q * 8);
  float4 Lb = *(const float4*)(Lp + q * 8 + 4);

  int ol0 = pos_lab[b];
  int ol1 = neg_lab[b * 8 + 0], ol2 = neg_lab[b * 8 + 1], ol3 = neg_lab[b * 8 + 2];
  int ol4 = neg_lab[b * 8 + 3], ol5 = neg_lab[b * 8 + 4], ol6 = neg_lab[b * 8 + 5];
  int ol7 = neg_lab[b * 8 + 6], ol8 = neg_lab[b * 8 + 7];

  // per-group labels for each round (round 2: all groups take pair 8)
  int oA = (g == 0) ? ol0 : (g == 1) ? ol1 : (g == 2) ? ol2 : ol3;
  int oB = (g == 0) ? ol4 : (g == 1) ? ol5 : (g == 2) ? ol6 : ol7;
  int oC = ol8;

  float4 RaA, RbA, RaB, RbB, RaC, RbC;
  {
    bool e = oA < ENT; int oid = e ? oA : oA - ENT;
    const float* Rp = (e ? out_ent : t1) + (size_t)oid * D + q * 8;
    RaA = *(const float4*)(Rp); RbA = *(const float4*)(Rp + 4);
  }
  {
    bool e = oB < ENT; int oid = e ? oB : oB - ENT;
    const float* Rp = (e ? out_ent : t1) + (size_t)oid * D + q * 8;
    RaB = *(const float4*)(Rp); RbB = *(const float4*)(Rp + 4);
  }
  {
    bool e = oC < ENT; int oid = e ? oC : oC - ENT;
    const float* Rp = (e ? out_ent : t1) + (size_t)oid * D + q * 8;
    RaC = *(const float4*)(Rp); RbC = *(const float4*)(Rp + 4);
  }

  float pA = La.x * RaA.x + La.y * RaA.y + La.z * RaA.z + La.w * RaA.w +
             Lb.x * RbA.x + Lb.y * RbA.y + Lb.z * RbA.z + Lb.w * RbA.w;
  float pB = La.x * RaB.x + La.y * RaB.y + La.z * RaB.z + La.w * RaB.w +
             Lb.x * RbB.x + Lb.y * RbB.y + Lb.z * RbB.z + Lb.w * RbB.w;
  float pC = La.x * RaC.x + La.y * RaC.y + La.z * RaC.z + La.w * RaC.w +
             Lb.x * RbC.x + Lb.y * RbC.y + Lb.z * RbC.z + Lb.w * RbC.w;
#pragma unroll
  for (int off = 8; off > 0; off >>= 1) {
    pA += __shfl_xor(pA, off, 64);
    pB += __shfl_xor(pB, off, 64);
    pC += __shfl_xor(pC, off, 64);
  }
  if (!ei) {  // wave-uniform, rare branch: rel-rel pairs read precomputed table
    if (oA >= ENT) pA = RR[iid * RELSZ + (oA - ENT)];
    if (oB >= ENT) pB = RR[iid * RELSZ + (oB - ENT)];
    if (oC >= ENT) pC = RR[iid * RELSZ + (oC - ENT)];
  }

  if (q == 0) {
    // round 0: pairs 0..3 (pair 0 = pos)
    if (g == 0) buf_pos[dest_pos[b]] = logsig(pA);
    else        buf_neg[dest_neg[b * 8 + g - 1]] = logsig(-pA);
    // round 1: pairs 4..7
    buf_neg[dest_neg[b * 8 + g + 3]] = logsig(-pB);
    // round 2: pair 8 (group 0 only)
    if (g == 0) buf_neg[dest_neg[b * 8 + 7]] = logsig(-pC);
  }
}

// out[j] = -(buf_pos[j] + sum_{t<8} buf_neg[8j+t])
__global__ void k_combine(const float* __restrict__ buf_pos, const float* __restrict__ buf_neg,
                          float* __restrict__ out) {
  int j = blockIdx.x * blockDim.x + threadIdx.x;
  if (j >= BATCH) return;
  float4 a = ((const float4*)buf_neg)[j * 2];
  float4 b = ((const float4*)buf_neg)[j * 2 + 1];
  float s = a.x + a.y + a.z + a.w + b.x + b.y + b.z + b.w;
  out[j] = -(buf_pos[j] + s);
}

extern "C" void kernel_launch(void* const* d_in, const int* in_sizes, int n_in,
                              void* d_out, int out_size, void* d_ws, size_t ws_size,
                              hipStream_t stream) {
  const float* in_ent  = (const float*)d_in[0];
  const float* out_ent = (const float*)d_in[1];
  const float* in_rel  = (const float*)d_in[2];
  const float* out_rel = (const float*)d_in[3];
  const float* in_map  = (const float*)d_in[4];
  const float* out_map = (const float*)d_in[5];
  const int* in_lab  = (const int*)d_in[6];
  const int* pos_lab = (const int*)d_in[7];
  const int* neg_lab = (const int*)d_in[8];

  char* ws = (char*)d_ws;
  float*   t1       = (float*)(ws + 0);
  float*   t2       = (float*)(ws + 32768);
  float*   RR       = (float*)(ws + 65536);
  int*     C        = (int*)(ws + 81920);
  uint8_t* keys     = (uint8_t*)(ws + 102400);
  int*     dest_pos = (int*)(ws + 397312);
  int*     dest_neg = (int*)(ws + 528384);
  float*   buf_pos  = (float*)(ws + 1576960);
  float*   buf_neg  = (float*)(ws + 1708032);
  float*   out      = (float*)d_out;

  k_tables<<<64, 128, 0, stream>>>(in_rel, out_rel, in_map, out_map, t1, t2, RR);
  k_count<<<1152, 256, 0, stream>>>(in_lab, pos_lab, neg_lab, keys, C);
  k_scan<<<1, 256, 0, stream>>>(C);
  k_dest<<<1152, 256, 0, stream>>>(keys, C, dest_pos, dest_neg);
  k_main<<<8192, 256, 0, stream>>>(in_ent, out_ent, t1, t2, RR,
                                   in_lab, pos_lab, neg_lab, dest_pos, dest_neg,
                                   buf_pos, buf_neg);
  k_combine<<<128, 256, 0, stream>>>(buf_pos, buf_neg, out);
}

// Round 3
// 46.745 us; speedup vs baseline: 2.3587x; 1.1537x over previous
//
#include <hip/hip_runtime.h>
#include <hip/hip_bf16.h>
#include <stdint.h>

#define ENT 250000
#define RELSZ 64
#define D 128
#define BATCH 32768
#define KNEG 8

// ---------------- workspace layout (byte offsets) ----------------
// t1       :       0 .. 32768    (64x128 f32)  out_rel - (n_inmap.out_rel) n_inmap
// t2       :   32768 .. 65536    (64x128 f32)  in_rel  - (n_outmap.in_rel) n_outmap
// RR       :   65536 .. 81920    (64x64  f32)  in_rel[i] . out_rel[p]
// C        :   81920 .. 100352   (4608 int)    block bucket counts -> exclusive scan
// rank_pos :  100352 .. 165888   (32768 u16)   block-local stable rank
// rank_neg :  165888 .. 690176   (262144 u16)

__device__ __forceinline__ float logsig(float x) {
  return fminf(x, 0.f) - log1pf(expf(-fabsf(x)));
}

// Fused: blocks [0,128) pos-count (+zero out), [128,1152) neg-count, [1152,1184) tables.
// Count layout: pos -> C[v*128 + blk]; neg -> C[512 + v*1024 + (blk-128)].
__global__ void k_prep(const float* __restrict__ in_rel, const float* __restrict__ out_rel,
                       const float* __restrict__ in_map, const float* __restrict__ out_map,
                       const int* __restrict__ in_lab, const int* __restrict__ pos_lab,
                       const int* __restrict__ neg_lab,
                       float* __restrict__ t1, float* __restrict__ t2, float* __restrict__ RR,
                       int* __restrict__ C, uint16_t* __restrict__ rank_pos,
                       uint16_t* __restrict__ rank_neg, float* __restrict__ out) {
  __shared__ float ls[4];
  __shared__ float sri[2][128];
  __shared__ int wc[4][4];
  int blk = blockIdx.x, t = threadIdx.x;

  if (blk >= 1152) {
    // ---- tables: 2 rel rows per block ----
    int sub = t >> 7, tt = t & 127;
    int p = (blk - 1152) * 2 + sub;
    float im = in_map[p * D + tt], om = out_map[p * D + tt];
    float ro = out_rel[p * D + tt], ri = in_rel[p * D + tt];
    // 4 reductions over each 128-thread half
    float v, r;
    float n_im, n_om;
    v = im * im;
#pragma unroll
    for (int off = 32; off > 0; off >>= 1) v += __shfl_xor(v, off, 64);
    if ((t & 63) == 0) ls[t >> 6] = v;
    __syncthreads();
    r = ls[sub * 2] + ls[sub * 2 + 1];
    n_im = im / fmaxf(sqrtf(r), 1e-12f);
    __syncthreads();
    v = om * om;
#pragma unroll
    for (int off = 32; off > 0; off >>= 1) v += __shfl_xor(v, off, 64);
    if ((t & 63) == 0) ls[t >> 6] = v;
    __syncthreads();
    r = ls[sub * 2] + ls[sub * 2 + 1];
    n_om = om / fmaxf(sqrtf(r), 1e-12f);
    __syncthreads();
    v = n_im * ro;
#pragma unroll
    for (int off = 32; off > 0; off >>= 1) v += __shfl_xor(v, off, 64);
    if ((t & 63) == 0) ls[t >> 6] = v;
    __syncthreads();
    float d1 = ls[sub * 2] + ls[sub * 2 + 1];
    __syncthreads();
    v = n_om * ri;
#pragma unroll
    for (int off = 32; off > 0; off >>= 1) v += __shfl_xor(v, off, 64);
    if ((t & 63) == 0) ls[t >> 6] = v;
    __syncthreads();
    float d2 = ls[sub * 2] + ls[sub * 2 + 1];
    t1[p * D + tt] = ro - d1 * n_im;
    t2[p * D + tt] = ri - d2 * n_om;
    sri[sub][tt] = ri;
    __syncthreads();
    // RR: 64 dots per row; threads [0,64) do row p0, [128,192) row p1
    int half = t >> 7, lq = t & 127;
    if (lq < RELSZ) {
      int pr = (blk - 1152) * 2 + half;
      const float* rq = out_rel + lq * D;
      const float* s = sri[half];
      float acc = 0.f;
#pragma unroll 8
      for (int d = 0; d < D; d += 4) {
        float4 r4 = *(const float4*)(rq + d);
        acc += s[d] * r4.x + s[d + 1] * r4.y + s[d + 2] * r4.z + s[d + 3] * r4.w;
      }
      RR[pr * RELSZ + lq] = acc;
    }
    return;
  }

  // ---- counting + stable block-local ranks ----
  int wave = t >> 6, lane = t & 63;
  int key, i;
  bool is_pos = blk < 128;
  if (is_pos) {
    i = blk * 256 + t;
    int il = in_lab[i], pl = pos_lab[i];
    key = ((il >= ENT) ? 2 : 0) | ((pl >= ENT) ? 1 : 0);
  } else {
    i = (blk - 128) * 256 + t;
    int il = in_lab[i >> 3], nl = neg_lab[i];
    key = ((il >= ENT) ? 2 : 0) | ((nl >= ENT) ? 1 : 0);
  }
  unsigned long long m[4];
#pragma unroll
  for (int v = 0; v < 4; v++) m[v] = __ballot(key == v);
  if (lane < 4) wc[wave][lane] = __popcll(m[lane]);
  int wrank = __popcll(m[key] & ((1ull << lane) - 1ull));
  __syncthreads();
  if (t < 4) {
    int s = wc[0][t] + wc[1][t] + wc[2][t] + wc[3][t];
    int idx = is_pos ? (t * 128 + blk) : (512 + t * 1024 + (blk - 128));
    C[idx] = s;
  }
  int wpre = 0;
  for (int w = 0; w < wave; w++) wpre += wc[w][key];
  uint16_t rk = (uint16_t)(wpre + wrank);
  if (is_pos) { rank_pos[i] = rk; out[i] = 0.f; }
  else        { rank_neg[i] = rk; }
}

// In-place exclusive scan of C[0..4607]. 1 block x 256 threads, 18 elems each.
__global__ void k_scan(int* __restrict__ C) {
  int t = threadIdx.x, lane = t & 63, w = t >> 6;
  int base = t * 18;
  int v[18];
  int s = 0;
#pragma unroll
  for (int j = 0; j < 18; j++) { v[j] = C[base + j]; s += v[j]; }
  int inc = s;
#pragma unroll
  for (int off = 1; off < 64; off <<= 1) {
    int x = __shfl_up(inc, off, 64);
    if (lane >= off) inc += x;
  }
  __shared__ int wsum[4];
  if (lane == 63) wsum[w] = inc;
  __syncthreads();
  int wpre = 0;
  for (int i = 0; i < w; i++) wpre += wsum[i];
  int run = wpre + inc - s;  // exclusive prefix of this thread's chunk
#pragma unroll
  for (int j = 0; j < 18; j++) { C[base + j] = run; run += v[j]; }
}

// Main: one wave per input row b. 8 lanes per pair (64 B/lane, 128B-contiguous per
// load instruction), 8 pairs round A + pair 8 round B (duplicated). Dest computed
// inline from key + block-local rank + scanned C; -logsig atomically added to out.
__global__ void k_main(const float* __restrict__ in_ent, const float* __restrict__ out_ent,
                       const float* __restrict__ t1, const float* __restrict__ t2,
                       const float* __restrict__ RR,
                       const int* __restrict__ in_lab, const int* __restrict__ pos_lab,
                       const int* __restrict__ neg_lab,
                       const int* __restrict__ C, const uint16_t* __restrict__ rank_pos,
                       const uint16_t* __restrict__ rank_neg, float* __restrict__ out) {
  int b = __builtin_amdgcn_readfirstlane((int)((blockIdx.x * blockDim.x + threadIdx.x) >> 6));
  int lane = threadIdx.x & 63;
  int q = lane & 7, g = lane >> 3;

  int il = in_lab[b];
  bool ei = il < ENT;
  int iid = ei ? il : il - ENT;
  const float* Lp = (ei ? in_ent + (size_t)iid * D : t2 + (size_t)iid * D) + q * 4;
  float4 L0 = *(const float4*)(Lp);
  float4 L1 = *(const float4*)(Lp + 32);
  float4 L2 = *(const float4*)(Lp + 64);
  float4 L3 = *(const float4*)(Lp + 96);

  int oA = (g == 0) ? pos_lab[b] : neg_lab[b * 8 + g - 1];
  int oB = neg_lab[b * 8 + 7];
  int keyA = (ei ? 0 : 2) | ((oA < ENT) ? 0 : 1);
  int keyB = (ei ? 0 : 2) | ((oB < ENT) ? 0 : 1);

  // destinations (only q==0 lanes; issued early to hide latency)
  int dA = 0, dB = 0;
  if (q == 0) {
    if (g == 0) {
      dA = C[keyA * 128 + (b >> 8)] + (int)rank_pos[b];
    } else {
      int i = b * 8 + g - 1;
      dA = (C[512 + keyA * 1024 + (i >> 8)] + (int)rank_neg[i] - BATCH) >> 3;
    }
    if (g == 7) {
      int i = b * 8 + 7;
      dB = (C[512 + keyB * 1024 + (i >> 8)] + (int)rank_neg[i] - BATCH) >> 3;
    }
  }

  bool eA = oA < ENT; int oidA = eA ? oA : oA - ENT;
  const float* RpA = (eA ? out_ent + (size_t)oidA * D : t1 + (size_t)oidA * D) + q * 4;
  float4 A0 = *(const float4*)(RpA);
  float4 A1 = *(const float4*)(RpA + 32);
  float4 A2 = *(const float4*)(RpA + 64);
  float4 A3 = *(const float4*)(RpA + 96);

  bool eB = oB < ENT; int oidB = eB ? oB : oB - ENT;
  const float* RpB = (eB ? out_ent + (size_t)oidB * D : t1 + (size_t)oidB * D) + q * 4;
  float4 B0 = *(const float4*)(RpB);
  float4 B1 = *(const float4*)(RpB + 32);
  float4 B2 = *(const float4*)(RpB + 64);
  float4 B3 = *(const float4*)(RpB + 96);

  float pA = L0.x * A0.x + L0.y * A0.y + L0.z * A0.z + L0.w * A0.w +
             L1.x * A1.x + L1.y * A1.y + L1.z * A1.z + L1.w * A1.w +
             L2.x * A2.x + L2.y * A2.y + L2.z * A2.z + L2.w * A2.w +
             L3.x * A3.x + L3.y * A3.y + L3.z * A3.z + L3.w * A3.w;
  float pB = L0.x * B0.x + L0.y * B0.y + L0.z * B0.z + L0.w * B0.w +
             L1.x * B1.x + L1.y * B1.y + L1.z * B1.z + L1.w * B1.w +
             L2.x * B2.x + L2.y * B2.y + L2.z * B2.z + L2.w * B2.w +
             L3.x * B3.x + L3.y * B3.y + L3.z * B3.z + L3.w * B3.w;
#pragma unroll
  for (int off = 4; off > 0; off >>= 1) {
    pA += __shfl_xor(pA, off, 64);
    pB += __shfl_xor(pB, off, 64);
  }

  if (q == 0) {
    float dotA = pA;
    if (!ei && oA >= ENT) dotA = RR[iid * RELSZ + (oA - ENT)];  // rel-rel pair
    float vA = (g == 0) ? logsig(dotA) : logsig(-dotA);
    atomicAdd(out + dA, -vA);
    if (g == 7) {
      float dotB = pB;
      if (!ei && oB >= ENT) dotB = RR[iid * RELSZ + (oB - ENT)];
      atomicAdd(out + dB, -logsig(-dotB));
    }
  }
}

extern "C" void kernel_launch(void* const* d_in, const int* in_sizes, int n_in,
                              void* d_out, int out_size, void* d_ws, size_t ws_size,
                              hipStream_t stream) {
  const float* in_ent  = (const float*)d_in[0];
  const float* out_ent = (const float*)d_in[1];
  const float* in_rel  = (const float*)d_in[2];
  const float* out_rel = (const float*)d_in[3];
  const float* in_map  = (const float*)d_in[4];
  const float* out_map = (const float*)d_in[5];
  const int* in_lab  = (const int*)d_in[6];
  const int* pos_lab = (const int*)d_in[7];
  const int* neg_lab = (const int*)d_in[8];

  char* ws = (char*)d_ws;
  float*    t1       = (float*)(ws + 0);
  float*    t2       = (float*)(ws + 32768);
  float*    RR       = (float*)(ws + 65536);
  int*      C        = (int*)(ws + 81920);
  uint16_t* rank_pos = (uint16_t*)(ws + 100352);
  uint16_t* rank_neg = (uint16_t*)(ws + 165888);
  float*    out      = (float*)d_out;

  k_prep<<<1184, 256, 0, stream>>>(in_rel, out_rel, in_map, out_map,
                                   in_lab, pos_lab, neg_lab,
                                   t1, t2, RR, C, rank_pos, rank_neg, out);
  k_scan<<<1, 256, 0, stream>>>(C);
  k_main<<<8192, 256, 0, stream>>>(in_ent, out_ent, t1, t2, RR,
                                   in_lab, pos_lab, neg_lab,
                                   C, rank_pos, rank_neg, out);
}